// Round 5
// baseline (201.000 us; speedup 1.0000x reference)
//
#include <hip/hip_runtime.h>
#include <stdint.h>

typedef unsigned short u16;
typedef unsigned int u32;
typedef __attribute__((ext_vector_type(8))) short bf16x8;
typedef __attribute__((ext_vector_type(4))) float f32x4;

#define DS 2048
#define NROWS 16384
#define MS 1024
#define K2 2048

__device__ __forceinline__ u16 f2bf(float f) {
  u32 u = __float_as_uint(f);
  u32 r = (u + 0x7fffu + ((u >> 16) & 1u)) >> 16;
  return (u16)r;
}
__device__ __forceinline__ float bf2f(u16 h) {
  return __uint_as_float(((u32)h) << 16);
}

// ---------------- f32 -> bf16 converts ----------------
__global__ __launch_bounds__(256) void k_conv(const float* __restrict__ in,
                                              u16* __restrict__ out, int n4) {
  int i = blockIdx.x * blockDim.x + threadIdx.x;
  int stride = gridDim.x * blockDim.x;
  for (; i < n4; i += stride) {
    float4 v = ((const float4*)in)[i];
    ushort4 o;
    o.x = f2bf(v.x); o.y = f2bf(v.y); o.z = f2bf(v.z); o.w = f2bf(v.w);
    ((ushort4*)out)[i] = o;
  }
}

__global__ __launch_bounds__(256) void k_conv_S(const float* __restrict__ in,
                                                u16* __restrict__ Sbf,
                                                u16* __restrict__ Bt, int n4) {
  int i = blockIdx.x * blockDim.x + threadIdx.x;
  int stride = gridDim.x * blockDim.x;
  for (; i < n4; i += stride) {
    float4 v = ((const float4*)in)[i];
    ushort4 o;
    o.x = f2bf(v.x); o.y = f2bf(v.y); o.z = f2bf(v.z); o.w = f2bf(v.w);
    ((ushort4*)Sbf)[i] = o;
    int m = i >> 9;
    int c4 = i & 511;
    ((ushort4*)Bt)[(size_t)m * 1024 + c4] = o;  // interleaved row 2m = S[m]
  }
}

// ---------------- async global->LDS, 16B per lane ----------------
__device__ __forceinline__ void gload16(const u16* g, u16* l) {
  __builtin_amdgcn_global_load_lds(
      (const __attribute__((address_space(1))) void*)g,
      (__attribute__((address_space(3))) void*)l, 16, 0, 0);
}

// ---------------- 64x128 bt-GEMM for V = S @ W^T (256 blocks) ----------------
__global__ __launch_bounds__(256, 2) void k_gemm_bt64(const u16* __restrict__ A,
                                                      const u16* __restrict__ Bt,
                                                      u16* __restrict__ C, int ldc,
                                                      int K) {
  __shared__ u16 lsA[64 * 32];
  __shared__ u16 lsB[128 * 32];
  const int tid = threadIdx.x;
  const int wid = tid >> 6;
  const int lane = tid & 63;
  const int brow = blockIdx.y * 64;
  const int bcol = blockIdx.x * 128;
  const int wm = wid >> 1;
  const int wn = wid & 1;

  f32x4 acc[2][4];
#pragma unroll
  for (int i = 0; i < 2; ++i)
#pragma unroll
    for (int j = 0; j < 4; ++j) acc[i][j] = (f32x4){0.f, 0.f, 0.f, 0.f};

  const int srow = lane >> 2;
  const int skoct = (lane & 3) * 8;
  const u16* gA = A + (size_t)(brow + wid * 16 + srow) * K + skoct;
  const u16* gB = Bt + (size_t)(bcol + wid * 32 + srow) * K + skoct;
  u16* lA = &lsA[(wid * 16) * 32];
  u16* lB0 = &lsB[(wid * 32) * 32];
  u16* lB1 = &lsB[(wid * 32 + 16) * 32];
  const size_t row16 = (size_t)16 * K;

  const int arow = wm * 32 + (lane & 15);
  const int bcr = wn * 64 + (lane & 15);
  const int koff = (lane >> 4) * 8;

  for (int kt = 0; kt < K; kt += 32) {
    gload16(gA + kt, lA);
    gload16(gB + kt, lB0);
    gload16(gB + kt + row16, lB1);
    __syncthreads();
    bf16x8 af[2], bfr[4];
#pragma unroll
    for (int i = 0; i < 2; ++i) af[i] = *(const bf16x8*)&lsA[(arow + i * 16) * 32 + koff];
#pragma unroll
    for (int i = 0; i < 4; ++i) bfr[i] = *(const bf16x8*)&lsB[(bcr + i * 16) * 32 + koff];
#pragma unroll
    for (int mi = 0; mi < 2; ++mi)
#pragma unroll
      for (int ni = 0; ni < 4; ++ni)
        acc[mi][ni] = __builtin_amdgcn_mfma_f32_16x16x32_bf16(af[mi], bfr[ni],
                                                              acc[mi][ni], 0, 0, 0);
    __syncthreads();
  }

  const int crow0 = brow + wm * 32 + (lane >> 4) * 4;
  const int ccol0 = bcol + wn * 64 + (lane & 15);
#pragma unroll
  for (int mi = 0; mi < 2; ++mi)
#pragma unroll
    for (int ni = 0; ni < 4; ++ni)
#pragma unroll
      for (int r = 0; r < 4; ++r)
        C[(size_t)(crow0 + mi * 16 + r) * ldc + (ccol0 + ni * 16)] = f2bf(acc[mi][ni][r]);
}

// ================= 256^2 4-phase GEMM + fused softmax epilogue ================
// C = Dbf[16384x2048] @ Bt[2048x2048]^T, Bt rows interleaved (2m=S, 2m+1=V).
// r5: 8 phases merged to 4 (32 MFMA/wave per barrier). A-frag reads at phase
// START (feed next phase); B-frag reads post-MFMA (WAR-locked); uniform
// LGKM(8)/VMW(4); all staging leads >=2 phases. Register-neutral vs r4.
#define SINV 0.022097086912079608f

#define DSR(d, a, IMM) \
  asm volatile("ds_read_b128 %0, %1 offset:%c2" : "=v"(d) : "v"(a), "n"(IMM))

#define RD_A0(k0, k1, dst)                              \
  DSR(dst[0][0], k0, 0);     DSR(dst[0][1], k1, 0);     \
  DSR(dst[1][0], k0, 2048);  DSR(dst[1][1], k1, 2048);  \
  DSR(dst[2][0], k0, 4096);  DSR(dst[2][1], k1, 4096);  \
  DSR(dst[3][0], k0, 6144);  DSR(dst[3][1], k1, 6144)
#define RD_A1(k0, k1, dst)                              \
  DSR(dst[0][0], k0, 16384); DSR(dst[0][1], k1, 16384); \
  DSR(dst[1][0], k0, 18432); DSR(dst[1][1], k1, 18432); \
  DSR(dst[2][0], k0, 20480); DSR(dst[2][1], k1, 20480); \
  DSR(dst[3][0], k0, 22528); DSR(dst[3][1], k1, 22528)
#define RD_B0(k0, k1, dst)                              \
  DSR(dst[0][0], k0, 0);     DSR(dst[0][1], k1, 0);     \
  DSR(dst[1][0], k0, 2048);  DSR(dst[1][1], k1, 2048)
#define RD_B1(k0, k1, dst)                              \
  DSR(dst[0][0], k0, 16384); DSR(dst[0][1], k1, 16384); \
  DSR(dst[1][0], k0, 18432); DSR(dst[1][1], k1, 18432)

#define MMAQ(AF, BQ, QM, QN)                                                       \
  do {                                                                             \
    _Pragma("unroll") for (int mi = 0; mi < 4; ++mi)                               \
        _Pragma("unroll") for (int ni = 0; ni < 2; ++ni) {                         \
      acc[QM][QN][mi][ni] = __builtin_amdgcn_mfma_f32_16x16x32_bf16(               \
          AF[mi][0], BQ[ni][0], acc[QM][QN][mi][ni], 0, 0, 0);                     \
      acc[QM][QN][mi][ni] = __builtin_amdgcn_mfma_f32_16x16x32_bf16(               \
          AF[mi][1], BQ[ni][1], acc[QM][QN][mi][ni], 0, 0, 0);                     \
    }                                                                              \
  } while (0)

#define LGKM(N)                                              \
  asm volatile("s_waitcnt lgkmcnt(" #N ")" ::: "memory");    \
  __builtin_amdgcn_sched_barrier(0)
#define VMW(N) asm volatile("s_waitcnt vmcnt(" #N ")" ::: "memory")
#define SB0() __builtin_amdgcn_sched_barrier(0)
#define PRIO1() __builtin_amdgcn_s_setprio(1)
#define PRIO0() __builtin_amdgcn_s_setprio(0)
#define BAR() __builtin_amdgcn_s_barrier()

// stage one half-tile (2 gloads): b buf, h row-half, kt k-elem offset
#define STGA(b, h, kt)                                                            \
  do {                                                                            \
    gload16(pA + (size_t)((h) * 128) * K2 + (kt),                                 \
            &lds[(b) * 32768 + (h) * 8192 + wid * 512]);                          \
    gload16(pA + (size_t)((h) * 128 + 64) * K2 + (kt),                            \
            &lds[(b) * 32768 + (h) * 8192 + 4096 + wid * 512]);                   \
  } while (0)
#define STGB(b, h, kt)                                                            \
  do {                                                                            \
    gload16(pB + (size_t)((h) * 128) * K2 + (kt),                                 \
            &lds[(b) * 32768 + 16384 + (h) * 8192 + wid * 512]);                  \
    gload16(pB + (size_t)((h) * 128 + 64) * K2 + (kt),                            \
            &lds[(b) * 32768 + 16384 + (h) * 8192 + 4096 + wid * 512]);           \
  } while (0)
#define STGB4(b, kt) do { STGB(b, 0, kt); STGB(b, 1, kt); } while (0)

__global__ __launch_bounds__(512, 2) void k_gemm8(const u16* __restrict__ A,
                                                  const u16* __restrict__ Bt,
                                                  float* __restrict__ Pnd) {
  extern __shared__ u16 lds[];
  const int tid = threadIdx.x;
  const int wid = tid >> 6;
  const int lane = tid & 63;
  const int bid = blockIdx.x;
  const int swz = (bid & 7) * 64 + (bid >> 3);
  const int by = swz >> 3, bx = swz & 7;
  const int brow = by * 256, bcol = bx * 256;
  const int wm = wid >> 2, wn = wid & 3;
  const int l15 = lane & 15, s0 = lane >> 4;

  // pre-swizzled global source (LDS dest linear; involution on 16B octets)
  const int tr = tid >> 3;
  const int scol = ((tid & 7) ^ (tr & 7)) << 3;
  const u16* pA = A + (size_t)(brow + tr) * K2 + scol;
  const u16* pB = Bt + (size_t)(bcol + tr) * K2 + scol;

  // ds_read base addresses (8 regs; k1 via XOR-64, buf1 via +65536)
  const u32 lb = (u32)(uintptr_t)(&lds[0]);
  const u32 xorp = ((u32)(s0 ^ (lane & 7))) << 4;
  const u32 aA00 = lb + ((u32)(wm * 64 + l15) << 7) + xorp;
  const u32 aA01 = aA00 ^ 64u;
  const u32 aA10 = aA00 + 65536u;
  const u32 aA11 = aA10 ^ 64u;
  const u32 aB00 = lb + 32768u + ((u32)(wn * 32 + l15) << 7) + xorp;
  const u32 aB01 = aB00 ^ 64u;
  const u32 aB10 = aB00 + 65536u;
  const u32 aB11 = aB10 ^ 64u;

  f32x4 acc[2][2][4][2];
#pragma unroll
  for (int a = 0; a < 2; ++a)
#pragma unroll
    for (int b = 0; b < 2; ++b)
#pragma unroll
      for (int c = 0; c < 4; ++c)
#pragma unroll
        for (int d = 0; d < 2; ++d) acc[a][b][c][d] = (f32x4){0.f, 0.f, 0.f, 0.f};

  bf16x8 afA[4][2], afB[4][2], bq0[2][2], bq1[2][2];

  // ---- prologue ----
  STGA(0, 0, 0); STGA(0, 1, 0); STGB4(0, 0);  // buf0 complete [8]
  STGA(1, 0, 64);                             // buf1.A.h0 [2]
  VMW(2);                                     // buf0 drained (leaves A.h0 pair)
  BAR();
  RD_A0(aA00, aA01, afA);                     // afA <- buf0.h0   [8r]
  RD_B0(aB00, aB01, bq0);                     // bq  <- buf0.B    [8r]
  RD_B1(aB00, aB01, bq1);
  STGB4(1, 64);                               // buf1.B [4] in flight

  int kb = 0;
#pragma unroll 1
  for (int j = 0; j < 15; ++j, kb += 128) {
    // MP1: buf0-top. A-reads: afB <- buf0.h1 (for MP2)
    RD_A1(aA00, aA01, afB);
    LGKM(8);
    PRIO1(); MMAQ(afA, bq0, 0, 0); MMAQ(afA, bq1, 0, 1); PRIO0();
    SB0();
    STGA(1, 1, kb + 64);       // buf1.A.h1   (read MP3-start)
    STGA(0, 0, kb + 128);      // buf0'.A.h0  (read MP4-start)
    VMW(4); BAR();
    // MP2: buf0-bottom. A-reads: afA <- buf1.h0 (for MP3)
    RD_A0(aA10, aA11, afA);
    LGKM(8);
    PRIO1(); MMAQ(afB, bq0, 1, 0); MMAQ(afB, bq1, 1, 1); PRIO0();
    SB0();
    RD_B0(aB10, aB11, bq0);    // bq <- buf1.B (for MP3+MP4)
    RD_B1(aB10, aB11, bq1);
    STGB4(0, kb + 128);        // buf0'.B     (read MP4-end)
    VMW(4); BAR();
    // MP3: buf1-top. A-reads: afB <- buf1.h1 (for MP4)
    RD_A1(aA10, aA11, afB);
    LGKM(8);
    PRIO1(); MMAQ(afA, bq0, 0, 0); MMAQ(afA, bq1, 0, 1); PRIO0();
    SB0();
    STGA(0, 1, kb + 128);      // buf0'.A.h1  (read MP1'-start)
    STGA(1, 0, kb + 192);      // buf1'.A.h0  (read MP2'-start)
    VMW(4); BAR();
    // MP4: buf1-bottom. A-reads: afA <- buf0'.h0 (for MP1')
    RD_A0(aA00, aA01, afA);
    LGKM(8);
    PRIO1(); MMAQ(afB, bq0, 1, 0); MMAQ(afB, bq1, 1, 1); PRIO0();
    SB0();
    RD_B0(aB00, aB01, bq0);    // bq <- buf0'.B (for MP1'+MP2')
    RD_B1(aB00, aB01, bq1);
    STGB4(1, kb + 192);        // buf1'.B     (read MP2'-end)
    VMW(4); BAR();
  }
  // ---- tail: tiles 30 (buf0) + 31 (buf1); kb == 1920 ----
  {
    // T1: buf0-top
    RD_A1(aA00, aA01, afB);
    LGKM(8);
    PRIO1(); MMAQ(afA, bq0, 0, 0); MMAQ(afA, bq1, 0, 1); PRIO0();
    SB0();
    STGA(1, 1, kb + 64);       // buf1.A.h1 (read T3-start)
    VMW(2);                    // drain buf1.B (read T2-end)
    BAR();
    // T2: buf0-bottom
    RD_A0(aA10, aA11, afA);
    LGKM(8);
    PRIO1(); MMAQ(afB, bq0, 1, 0); MMAQ(afB, bq1, 1, 1); PRIO0();
    SB0();
    RD_B0(aB10, aB11, bq0);
    RD_B1(aB10, aB11, bq1);
    VMW(0);                    // drain buf1.A.h1 gloads
    BAR();
    // T3: buf1-top
    RD_A1(aA10, aA11, afB);
    LGKM(8);
    PRIO1(); MMAQ(afA, bq0, 0, 0); MMAQ(afA, bq1, 0, 1); PRIO0();
    SB0();
    // T4: buf1-bottom (no staging, no barrier needed)
    LGKM(0);
    PRIO1(); MMAQ(afB, bq0, 1, 0); MMAQ(afB, bq1, 1, 1); PRIO0();
  }

  // ---------------- fused epilogue ----------------
  // col = qn*128 + wn*32 + ni*16 + l15 (even=s, odd=g); row = qm*128+wm*64+mi*16+s0*4+r
  __syncthreads();
  float* red = (float*)&lds[0];

#pragma unroll
  for (int qm = 0; qm < 2; ++qm)
#pragma unroll
    for (int mi = 0; mi < 4; ++mi)
#pragma unroll
      for (int r = 0; r < 4; ++r) {
        float num = 0.f, den = 0.f;
#pragma unroll
        for (int qn = 0; qn < 2; ++qn)
#pragma unroll
          for (int ni = 0; ni < 2; ++ni) {
            float v = acc[qm][qn][mi][ni][r];
            float g = __shfl_xor(v, 1);
            float e = __expf(v * SINV);
            num += e * g;
            den += e;
          }
        num += __shfl_xor(num, 2); den += __shfl_xor(den, 2);
        num += __shfl_xor(num, 4); den += __shfl_xor(den, 4);
        num += __shfl_xor(num, 8); den += __shfl_xor(den, 8);
        if (l15 == 0) {
          int slot = qm * 16 + mi * 4 + r;
          red[((wid * 32 + slot) * 4 + s0) * 2 + 0] = num;
          red[((wid * 32 + slot) * 4 + s0) * 2 + 1] = den;
        }
      }
  __syncthreads();
  {
    int rloc = tid >> 1, which = tid & 1;
    int qm = rloc >> 7, wmr = (rloc >> 6) & 1, mi = (rloc >> 4) & 3;
    int lg = (rloc >> 2) & 3, r = rloc & 3;
    int slot = qm * 16 + mi * 4 + r;
    float v = 0.f;
#pragma unroll
    for (int w2 = 0; w2 < 4; ++w2)
      v += red[(((wmr * 4 + w2) * 32 + slot) * 4 + lg) * 2 + which];
    Pnd[((size_t)(brow + rloc) * 8 + bx) * 2 + which] = v;
  }
}

// ---------------- per-row finish ----------------
__global__ __launch_bounds__(256) void k_rowfinal(const float* __restrict__ Pnd,
                                                  float* __restrict__ part) {
  int row = blockIdx.x * 256 + threadIdx.x;
  const float4* p = (const float4*)(Pnd + (size_t)row * 16);
  float num = 0.f, den = 0.f;
#pragma unroll
  for (int i = 0; i < 4; ++i) {
    float4 v = p[i];
    num += v.x + v.z;
    den += v.y + v.w;
  }
  float logit = num / den;
  float ls = (logit >= 0.f) ? -log1pf(__expf(-logit))
                            : (logit - log1pf(__expf(logit)));
  __shared__ float red[4];
#pragma unroll
  for (int off = 32; off > 0; off >>= 1) ls += __shfl_down(ls, off);
  if ((threadIdx.x & 63) == 0) red[threadIdx.x >> 6] = ls;
  __syncthreads();
  if (threadIdx.x == 0) part[blockIdx.x] = red[0] + red[1] + red[2] + red[3];
}

__global__ __launch_bounds__(64) void k_final64(const float* __restrict__ part,
                                                float* __restrict__ out) {
  float v = part[threadIdx.x];
#pragma unroll
  for (int off = 32; off > 0; off >>= 1) v += __shfl_down(v, off);
  if (threadIdx.x == 0) out[0] = v;
}

extern "C" void kernel_launch(void* const* d_in, const int* in_sizes, int n_in,
                              void* d_out, int out_size, void* d_ws, size_t ws_size,
                              hipStream_t stream) {
  const float* D = (const float*)d_in[0];
  const float* S = (const float*)d_in[1];
  const float* W = (const float*)d_in[2];

  char* w = (char*)d_ws;
  u16* Dbf = (u16*)w; w += (size_t)NROWS * DS * 2;       // 67 MB
  u16* Bt = (u16*)w;  w += (size_t)DS * DS * 2;          // 8 MB (interleaved S/V)
  u16* Wbf = (u16*)w; w += (size_t)DS * DS * 2;          // 8 MB
  u16* Sbf = (u16*)w; w += (size_t)MS * DS * 2;          // 4 MB
  float* Pnd = (float*)w; w += (size_t)NROWS * 16 * 4;   // 1 MB
  float* part = (float*)w;                               // 256 B

  (void)hipFuncSetAttribute((const void*)k_gemm8,
                            hipFuncAttributeMaxDynamicSharedMemorySize, 131072);

  k_conv<<<1024, 256, 0, stream>>>(W, Wbf, DS * DS / 4);
  k_conv_S<<<512, 256, 0, stream>>>(S, Sbf, Bt, MS * DS / 4);
  k_conv<<<2048, 256, 0, stream>>>(D, Dbf, NROWS * DS / 4);

  // V = S @ W^T into Bt odd rows (ldc = 4096, base = Bt + 2048)
  k_gemm_bt64<<<dim3(DS / 128, MS / 64), 256, 0, stream>>>(
      Sbf, Wbf, Bt + DS, 2 * DS, DS);

  k_gemm8<<<512, 512, 131072, stream>>>(Dbf, Bt, Pnd);

  k_rowfinal<<<NROWS / 256, 256, 0, stream>>>(Pnd, part);
  k_final64<<<1, 64, 0, stream>>>(part, (float*)d_out);
}